// Round 6
// baseline (302.863 us; speedup 1.0000x reference)
//
#include <hip/hip_runtime.h>
#include <hip/hip_bf16.h>

// B=4, S=1024, D=1024, H=16, d_k=64, MAX_REL=128 (NP=257)
#define NP 257

typedef __attribute__((ext_vector_type(8))) short short8;
typedef __attribute__((ext_vector_type(4))) float f32x4;

__device__ __forceinline__ unsigned short f32_to_bf16(float f) {
    unsigned int u = __float_as_uint(f);
    unsigned int r = (u + 0x7FFFu + ((u >> 16) & 1u)) >> 16;
    return (unsigned short)r;
}
__device__ __forceinline__ float bf16_to_f32(unsigned short u) {
    return __uint_as_float(((unsigned int)u) << 16);
}

// ---------------- fp32 -> bf16 pack, 8 elems/thread; grid.y selects buffer pair
__global__ __launch_bounds__(256) void cvt_bf16_2(const float* __restrict__ s0,
                                                  unsigned short* __restrict__ d0,
                                                  const float* __restrict__ s1,
                                                  unsigned short* __restrict__ d1,
                                                  int n8)
{
    int i = blockIdx.x * 256 + threadIdx.x;
    if (i >= n8) return;
    const float* src = blockIdx.y ? s1 : s0;
    unsigned short* dst = blockIdx.y ? d1 : d0;
    const float4* s = reinterpret_cast<const float4*>(src) + (size_t)i * 2;
    float4 a = s[0], b = s[1];
    union { unsigned short u[8]; uint4 v; } p;
    p.u[0] = f32_to_bf16(a.x); p.u[1] = f32_to_bf16(a.y);
    p.u[2] = f32_to_bf16(a.z); p.u[3] = f32_to_bf16(a.w);
    p.u[4] = f32_to_bf16(b.x); p.u[5] = f32_to_bf16(b.y);
    p.u[6] = f32_to_bf16(b.z); p.u[7] = f32_to_bf16(b.w);
    reinterpret_cast<uint4*>(dst)[i] = p.v;
}

// ---------------- MFMA projection, both GEMMs in one dispatch (blockIdx.z).
// Tile 128x128x64, 256 thr = 4 waves (2x2), wave tile 64x64 (4x4 frags).
__global__ __launch_bounds__(256) void proj_mfma(const unsigned short* __restrict__ Xq,
                                                 const unsigned short* __restrict__ Wqb,
                                                 const float* __restrict__ bq,
                                                 unsigned short* __restrict__ outq,
                                                 const unsigned short* __restrict__ Xk,
                                                 const unsigned short* __restrict__ Wkb,
                                                 const float* __restrict__ bk,
                                                 unsigned short* __restrict__ outk)
{
    __shared__ unsigned short As[8192];
    __shared__ unsigned short Bs[8192];
    const unsigned short* Xb = blockIdx.z ? Xk : Xq;
    const unsigned short* Wb = blockIdx.z ? Wkb : Wqb;
    const float* bias        = blockIdx.z ? bk : bq;
    unsigned short* outb     = blockIdx.z ? outk : outq;

    const int tid = threadIdx.x;
    const int lane = tid & 63;
    const int w = tid >> 6;
    const int wi = w >> 1, wj = w & 1;
    const int bm = blockIdx.x * 128, bn = blockIdx.y * 128;
    const int r15 = lane & 15, g = lane >> 4;

    f32x4 acc[4][4];
    #pragma unroll
    for (int i = 0; i < 4; ++i)
        #pragma unroll
        for (int j = 0; j < 4; ++j) acc[i][j] = (f32x4){0.f, 0.f, 0.f, 0.f};

    size_t offA[4], offB[4];
    #pragma unroll
    for (int it = 0; it < 4; ++it) {
        int f = it * 256 + tid, row = f >> 3, cl = (f & 7) ^ (row & 7);
        offA[it] = (size_t)(bm + row) * 1024 + cl * 8;
        offB[it] = (size_t)(bn + row) * 1024 + cl * 8;
    }
    const int ldsbase = w * 512;

    for (int kt = 0; kt < 16; ++kt) {
        const int k0 = kt * 64;
        #pragma unroll
        for (int it = 0; it < 4; ++it)
            __builtin_amdgcn_global_load_lds(
                (const __attribute__((address_space(1))) void*)(Xb + offA[it] + k0),
                (__attribute__((address_space(3))) void*)(As + it * 2048 + ldsbase), 16, 0, 0);
        #pragma unroll
        for (int it = 0; it < 4; ++it)
            __builtin_amdgcn_global_load_lds(
                (const __attribute__((address_space(1))) void*)(Wb + offB[it] + k0),
                (__attribute__((address_space(3))) void*)(Bs + it * 2048 + ldsbase), 16, 0, 0);
        __syncthreads();

        #pragma unroll
        for (int kk = 0; kk < 2; ++kk) {
            const int c = kk * 4 + g;
            short8 a[4], bfr[4];
            #pragma unroll
            for (int ti = 0; ti < 4; ++ti) {
                const int ra = wi * 64 + ti * 16 + r15;
                a[ti] = *(const short8*)&As[(ra * 8 + (c ^ (ra & 7))) * 8];
            }
            #pragma unroll
            for (int tj = 0; tj < 4; ++tj) {
                const int rb = wj * 64 + tj * 16 + r15;
                bfr[tj] = *(const short8*)&Bs[(rb * 8 + (c ^ (rb & 7))) * 8];
            }
            #pragma unroll
            for (int ti = 0; ti < 4; ++ti)
                #pragma unroll
                for (int tj = 0; tj < 4; ++tj)
                    acc[ti][tj] = __builtin_amdgcn_mfma_f32_16x16x32_bf16(a[ti], bfr[tj], acc[ti][tj], 0, 0, 0);
        }
        __syncthreads();
    }

    #pragma unroll
    for (int tj = 0; tj < 4; ++tj) {
        const int n = bn + wj * 64 + tj * 16 + r15;
        const float bv = bias[n];
        #pragma unroll
        for (int ti = 0; ti < 4; ++ti) {
            const int orow = bm + wi * 64 + ti * 16 + (g << 2);
            #pragma unroll
            for (int r = 0; r < 4; ++r)
                outb[(size_t)(orow + r) * 1024 + n] = f32_to_bf16(acc[ti][tj][r] + bv);
        }
    }
}

// ---------------- fused qmean + reldot: rdot[b,i,p] = scale*dot(mean_h q, relk[p])
__global__ __launch_bounds__(256) void relrow(const unsigned short* __restrict__ qb,
                                              const float* __restrict__ relk,
                                              float* __restrict__ rdot)
{
    __shared__ __align__(16) float qm[64];
    const int bi = blockIdx.x;                  // b*1024 + i, 4096 blocks
    const int t = threadIdx.x;
    if (t < 64) {
        const unsigned short* qrow = qb + ((size_t)bi << 10);
        float s = 0.f;
        #pragma unroll
        for (int h2 = 0; h2 < 16; ++h2) s += bf16_to_f32(qrow[h2 * 64 + t]);
        qm[t] = s * 0.0625f;
    }
    __syncthreads();
    const float4* qm4 = reinterpret_cast<const float4*>(qm);
    for (int p = t; p < NP; p += 256) {
        const float4* rk4 = reinterpret_cast<const float4*>(relk + (size_t)p * 64);
        float s0 = 0.f, s1 = 0.f, s2 = 0.f, s3 = 0.f;
        #pragma unroll
        for (int d4 = 0; d4 < 16; ++d4) {
            float4 a = qm4[d4];
            float4 b = rk4[d4];
            s0 = fmaf(a.x, b.x, s0);
            s1 = fmaf(a.y, b.y, s1);
            s2 = fmaf(a.z, b.z, s2);
            s3 = fmaf(a.w, b.w, s3);
        }
        rdot[(size_t)bi * NP + p] = (s0 + s1 + s2 + s3) * 0.125f;
    }
}

// ---------------- mask -> bitmask, layout mb[(b*16 + j/64)<<10 | i] (u64)
__global__ __launch_bounds__(1024) void maskbits(const int* __restrict__ mask,
                                                 unsigned long long* __restrict__ mb)
{
    const int row = blockIdx.x;                 // b*1024 + i
    const int j = threadIdx.x;
    unsigned long long bal = __ballot(mask[((size_t)row << 10) + j] != 0);
    if ((j & 63) == 0) {
        const int b = row >> 10, i = row & 1023;
        mb[(((size_t)(b * 16 + (j >> 6))) << 10) + i] = bal;
    }
}

// ---------------- attn3: 2-pass register softmax, no score storage.
// Block 256 thr / 4 waves: 16 q-rows (i0..i0+15), wave w owns j in [256w,256w+256).
// Swapped mfma(K,Q): lane r15 = q-row, owns 4 consecutive j (g*4+reg).
// Pass1: sum of exp (wave shfl + tiny LDS cross-wave). Pass2: recompute exp,
// scale, store float4 from registers. Masked -> e=0 via bitmask nibble.
__global__ __launch_bounds__(256) void attn3(const unsigned short* __restrict__ qb,
                                             const unsigned short* __restrict__ kb,
                                             const unsigned long long* __restrict__ mb,
                                             const float* __restrict__ rdot,
                                             float* __restrict__ out)
{
    __shared__ float redsum[4][16];
    const int i0 = blockIdx.x * 16;
    const int h = blockIdx.y, b = blockIdx.z;
    const int tid = threadIdx.x, lane = tid & 63, w = tid >> 6;
    const int r15 = lane & 15, g = lane >> 4;
    const size_t qkbase = ((size_t)b << 20) + h * 64;

    const unsigned short* qp = qb + qkbase + (size_t)(i0 + r15) * 1024 + 8 * g;
    short8 qf0 = *(const short8*)qp;
    short8 qf1 = *(const short8*)(qp + 32);

    const int i = i0 + r15;                      // this lane's q-row
    const float* rr = rdot + (size_t)(b * 1024 + i) * NP + 128;
    const float rvlo = rr[-128], rvhi = rr[128];
    const unsigned long long* mrow = mb + (((size_t)b) << 14) + i;   // + (j>>6)<<10
    const int n0w = w * 256;
    const size_t obase = ((size_t)((b * 16 + h) * 1024 + i)) << 10;

    float ps = 0.f;
    float inv = 0.f;

    #pragma unroll 1
    for (int pass = 0; pass < 2; ++pass) {
        #pragma unroll 4
        for (int jt = 0; jt < 16; ++jt) {
            const int j0 = n0w + jt * 16;
            const unsigned short* kp = kb + qkbase + (size_t)(j0 + r15) * 1024 + 8 * g;
            short8 kf0 = *(const short8*)kp;
            short8 kf1 = *(const short8*)(kp + 32);
            f32x4 acc = (f32x4){0.f, 0.f, 0.f, 0.f};
            acc = __builtin_amdgcn_mfma_f32_16x16x32_bf16(kf0, qf0, acc, 0, 0, 0);
            acc = __builtin_amdgcn_mfma_f32_16x16x32_bf16(kf1, qf1, acc, 0, 0, 0);

            const int jc = j0 + (g << 2);
            const unsigned long long mw = mrow[(size_t)(j0 >> 6) << 10];
            const unsigned int nib = (unsigned int)(mw >> (jc & 63)) & 0xFu;

            // rel bias: wave-uniform classification (j0, i0 uniform)
            float rv0, rv1, rv2, rv3;
            const int lo = j0 - (i0 + 15), hi = j0 + 15 - i0;
            if (hi <= -129) {                    // fully left-clipped
                rv0 = rv1 = rv2 = rv3 = rvlo;
            } else if (lo >= 129) {              // fully right-clipped
                rv0 = rv1 = rv2 = rv3 = rvhi;
            } else {
                const int d0 = jc - i;
                int dd;
                dd = min(max(d0 + 0, -128), 128); rv0 = rr[dd];
                dd = min(max(d0 + 1, -128), 128); rv1 = rr[dd];
                dd = min(max(d0 + 2, -128), 128); rv2 = rr[dd];
                dd = min(max(d0 + 3, -128), 128); rv3 = rr[dd];
            }

            const float e0 = (nib & 1u) ? __expf(fmaf(acc[0], 0.125f, rv0)) : 0.f;
            const float e1 = (nib & 2u) ? __expf(fmaf(acc[1], 0.125f, rv1)) : 0.f;
            const float e2 = (nib & 4u) ? __expf(fmaf(acc[2], 0.125f, rv2)) : 0.f;
            const float e3 = (nib & 8u) ? __expf(fmaf(acc[3], 0.125f, rv3)) : 0.f;

            if (pass == 0) {
                ps += (e0 + e1) + (e2 + e3);
            } else {
                float4 v = {e0 * inv, e1 * inv, e2 * inv, e3 * inv};
                *reinterpret_cast<float4*>(out + obase + jc) = v;
            }
        }
        if (pass == 0) {
            ps += __shfl_xor(ps, 16, 64);
            ps += __shfl_xor(ps, 32, 64);
            if (lane < 16) redsum[w][r15] = ps;
            __syncthreads();
            inv = 1.0f / (redsum[0][r15] + redsum[1][r15] + redsum[2][r15] + redsum[3][r15]);
        }
    }
}

extern "C" void kernel_launch(void* const* d_in, const int* in_sizes, int n_in,
                              void* d_out, int out_size, void* d_ws, size_t ws_size,
                              hipStream_t stream) {
    const float* query = (const float*)d_in[0];
    const float* key   = (const float*)d_in[1];
    const int*   mask  = (const int*)d_in[2];
    const float* Wq    = (const float*)d_in[3];
    const float* bq    = (const float*)d_in[4];
    const float* Wk    = (const float*)d_in[5];
    const float* bk    = (const float*)d_in[6];
    const float* relk  = (const float*)d_in[7];

    char* ws = (char*)d_ws;
    unsigned short* qB     = (unsigned short*)(ws);                  // 8 MB  q bf16
    unsigned short* kB     = (unsigned short*)(ws + (8u  << 20));    // 8 MB  k bf16
    unsigned short* queryb = (unsigned short*)(ws + (16u << 20));    // 8 MB (dead after proj)
    unsigned short* keyb   = (unsigned short*)(ws + (24u << 20));    // 8 MB (dead after proj)
    unsigned short* Wqb    = (unsigned short*)(ws + (32u << 20));    // 2 MB
    unsigned short* Wkb    = (unsigned short*)(ws + (34u << 20));    // 2 MB
    float*          rdot   = (float*)(ws + (37u << 20));             // 4.21 MB
    unsigned long long* mbB = (unsigned long long*)(ws + (16u << 20)); // 512 KB, after proj
    float*          out    = (float*)d_out;

    cvt_bf16_2<<<dim3(2048, 2), 256, 0, stream>>>(query, queryb, key, keyb, 524288);
    cvt_bf16_2<<<dim3(512, 2),  256, 0, stream>>>(Wq, Wqb, Wk, Wkb, 131072);

    proj_mfma<<<dim3(32, 8, 2), 256, 0, stream>>>(queryb, Wqb, bq, qB,
                                                  keyb,   Wkb, bk, kB);

    relrow<<<4096, 256, 0, stream>>>(qB, relk, rdot);
    maskbits<<<4096, 1024, 0, stream>>>(mask, mbB);

    attn3<<<dim3(64, 16, 4), 256, 0, stream>>>(qB, kB, mbB, rdot, out);
}

// Round 7
// 184.188 us; speedup vs baseline: 1.6443x; 1.6443x over previous
//
#include <hip/hip_runtime.h>
#include <hip/hip_bf16.h>

// B=4, S=1024, D=1024, H=16, d_k=64, MAX_REL=128 (NP=257)
#define NP 257

typedef __attribute__((ext_vector_type(8))) short short8;
typedef __attribute__((ext_vector_type(4))) float f32x4;

__device__ __forceinline__ unsigned short f32_to_bf16(float f) {
    unsigned int u = __float_as_uint(f);
    unsigned int r = (u + 0x7FFFu + ((u >> 16) & 1u)) >> 16;
    return (unsigned short)r;
}
__device__ __forceinline__ float bf16_to_f32(unsigned short u) {
    return __uint_as_float(((unsigned int)u) << 16);
}

// ---------------- fp32 -> bf16 pack, 8 elems/thread; grid.y selects buffer pair
__global__ __launch_bounds__(256) void cvt_bf16_2(const float* __restrict__ s0,
                                                  unsigned short* __restrict__ d0,
                                                  const float* __restrict__ s1,
                                                  unsigned short* __restrict__ d1,
                                                  int n8)
{
    int i = blockIdx.x * 256 + threadIdx.x;
    if (i >= n8) return;
    const float* src = blockIdx.y ? s1 : s0;
    unsigned short* dst = blockIdx.y ? d1 : d0;
    const float4* s = reinterpret_cast<const float4*>(src) + (size_t)i * 2;
    float4 a = s[0], b = s[1];
    union { unsigned short u[8]; uint4 v; } p;
    p.u[0] = f32_to_bf16(a.x); p.u[1] = f32_to_bf16(a.y);
    p.u[2] = f32_to_bf16(a.z); p.u[3] = f32_to_bf16(a.w);
    p.u[4] = f32_to_bf16(b.x); p.u[5] = f32_to_bf16(b.y);
    p.u[6] = f32_to_bf16(b.z); p.u[7] = f32_to_bf16(b.w);
    reinterpret_cast<uint4*>(dst)[i] = p.v;
}

// ---------------- MFMA projection, both GEMMs in one dispatch (blockIdx.z).
// Tile 128x128x64, 256 thr = 4 waves (2x2), wave tile 64x64 (4x4 frags).
__global__ __launch_bounds__(256) void proj_mfma(const unsigned short* __restrict__ Xq,
                                                 const unsigned short* __restrict__ Wqb,
                                                 const float* __restrict__ bq,
                                                 unsigned short* __restrict__ outq,
                                                 const unsigned short* __restrict__ Xk,
                                                 const unsigned short* __restrict__ Wkb,
                                                 const float* __restrict__ bk,
                                                 unsigned short* __restrict__ outk)
{
    __shared__ unsigned short As[8192];
    __shared__ unsigned short Bs[8192];
    const unsigned short* Xb = blockIdx.z ? Xk : Xq;
    const unsigned short* Wb = blockIdx.z ? Wkb : Wqb;
    const float* bias        = blockIdx.z ? bk : bq;
    unsigned short* outb     = blockIdx.z ? outk : outq;

    const int tid = threadIdx.x;
    const int lane = tid & 63;
    const int w = tid >> 6;
    const int wi = w >> 1, wj = w & 1;
    const int bm = blockIdx.x * 128, bn = blockIdx.y * 128;
    const int r15 = lane & 15, g = lane >> 4;

    f32x4 acc[4][4];
    #pragma unroll
    for (int i = 0; i < 4; ++i)
        #pragma unroll
        for (int j = 0; j < 4; ++j) acc[i][j] = (f32x4){0.f, 0.f, 0.f, 0.f};

    size_t offA[4], offB[4];
    #pragma unroll
    for (int it = 0; it < 4; ++it) {
        int f = it * 256 + tid, row = f >> 3, cl = (f & 7) ^ (row & 7);
        offA[it] = (size_t)(bm + row) * 1024 + cl * 8;
        offB[it] = (size_t)(bn + row) * 1024 + cl * 8;
    }
    const int ldsbase = w * 512;

    for (int kt = 0; kt < 16; ++kt) {
        const int k0 = kt * 64;
        #pragma unroll
        for (int it = 0; it < 4; ++it)
            __builtin_amdgcn_global_load_lds(
                (const __attribute__((address_space(1))) void*)(Xb + offA[it] + k0),
                (__attribute__((address_space(3))) void*)(As + it * 2048 + ldsbase), 16, 0, 0);
        #pragma unroll
        for (int it = 0; it < 4; ++it)
            __builtin_amdgcn_global_load_lds(
                (const __attribute__((address_space(1))) void*)(Wb + offB[it] + k0),
                (__attribute__((address_space(3))) void*)(Bs + it * 2048 + ldsbase), 16, 0, 0);
        __syncthreads();

        #pragma unroll
        for (int kk = 0; kk < 2; ++kk) {
            const int c = kk * 4 + g;
            short8 a[4], bfr[4];
            #pragma unroll
            for (int ti = 0; ti < 4; ++ti) {
                const int ra = wi * 64 + ti * 16 + r15;
                a[ti] = *(const short8*)&As[(ra * 8 + (c ^ (ra & 7))) * 8];
            }
            #pragma unroll
            for (int tj = 0; tj < 4; ++tj) {
                const int rb = wj * 64 + tj * 16 + r15;
                bfr[tj] = *(const short8*)&Bs[(rb * 8 + (c ^ (rb & 7))) * 8];
            }
            #pragma unroll
            for (int ti = 0; ti < 4; ++ti)
                #pragma unroll
                for (int tj = 0; tj < 4; ++tj)
                    acc[ti][tj] = __builtin_amdgcn_mfma_f32_16x16x32_bf16(a[ti], bfr[tj], acc[ti][tj], 0, 0, 0);
        }
        __syncthreads();
    }

    #pragma unroll
    for (int tj = 0; tj < 4; ++tj) {
        const int n = bn + wj * 64 + tj * 16 + r15;
        const float bv = bias[n];
        #pragma unroll
        for (int ti = 0; ti < 4; ++ti) {
            const int orow = bm + wi * 64 + ti * 16 + (g << 2);
            #pragma unroll
            for (int r = 0; r < 4; ++r)
                outb[(size_t)(orow + r) * 1024 + n] = f32_to_bf16(acc[ti][tj][r] + bv);
        }
    }
}

// ---------------- fused qmean + reldot: rdot[b,i,p] = scale*dot(mean_h q, relk[p])
__global__ __launch_bounds__(256) void relrow(const unsigned short* __restrict__ qb,
                                              const float* __restrict__ relk,
                                              float* __restrict__ rdot)
{
    __shared__ __align__(16) float qm[64];
    const int bi = blockIdx.x;                  // b*1024 + i, 4096 blocks
    const int t = threadIdx.x;
    if (t < 64) {
        const unsigned short* qrow = qb + ((size_t)bi << 10);
        float s = 0.f;
        #pragma unroll
        for (int h2 = 0; h2 < 16; ++h2) s += bf16_to_f32(qrow[h2 * 64 + t]);
        qm[t] = s * 0.0625f;
    }
    __syncthreads();
    const float4* qm4 = reinterpret_cast<const float4*>(qm);
    for (int p = t; p < NP; p += 256) {
        const float4* rk4 = reinterpret_cast<const float4*>(relk + (size_t)p * 64);
        float s0 = 0.f, s1 = 0.f, s2 = 0.f, s3 = 0.f;
        #pragma unroll
        for (int d4 = 0; d4 < 16; ++d4) {
            float4 a = qm4[d4];
            float4 b = rk4[d4];
            s0 = fmaf(a.x, b.x, s0);
            s1 = fmaf(a.y, b.y, s1);
            s2 = fmaf(a.z, b.z, s2);
            s3 = fmaf(a.w, b.w, s3);
        }
        rdot[(size_t)bi * NP + p] = (s0 + s1 + s2 + s3) * 0.125f;
    }
}

// ---------------- mask -> bitmask, layout mb[(b*16 + j/64)<<10 | i] (u64)
__global__ __launch_bounds__(1024) void maskbits(const int* __restrict__ mask,
                                                 unsigned long long* __restrict__ mb)
{
    const int row = blockIdx.x;                 // b*1024 + i
    const int j = threadIdx.x;
    unsigned long long bal = __ballot(mask[((size_t)row << 10) + j] != 0);
    if ((j & 63) == 0) {
        const int b = row >> 10, i = row & 1023;
        mb[(((size_t)(b * 16 + (j >> 6))) << 10) + i] = bal;
    }
}

// ---------------- attn4: QBLK=32, one-pass fused exp, bf16 e staged in LDS.
// Block 256 thr / 4 waves: rows i0..i0+31 (two 16-row groups), wave w owns
// j in [256w, 256w+256). Swapped mfma(K,Q): lane r15 = q-row within group,
// owns 4 consecutive j. Each K B-frag feeds 4 MFMAs (2 row groups x 2 k-halves).
// Mask via hoisted u64 bitmask words; rel bias via uniform clip classification.
__global__ __launch_bounds__(256) void attn4(const unsigned short* __restrict__ qb,
                                             const unsigned short* __restrict__ kb,
                                             const unsigned long long* __restrict__ mb,
                                             const float* __restrict__ rdot,
                                             float* __restrict__ out)
{
    __shared__ unsigned short e_lds[32 * 1024];   // 64 KB
    __shared__ float redsum[4][32];
    const int i0 = blockIdx.x * 32;
    const int h = blockIdx.y, b = blockIdx.z;
    const int tid = threadIdx.x, lane = tid & 63, w = tid >> 6;
    const int r15 = lane & 15, g = lane >> 4;
    const size_t qkbase = ((size_t)b << 20) + h * 64;

    // Q frags for both row groups
    const unsigned short* qp0 = qb + qkbase + (size_t)(i0 + r15) * 1024 + 8 * g;
    const unsigned short* qp1 = qp0 + (16 << 10);
    short8 qf00 = *(const short8*)qp0,        qf01 = *(const short8*)(qp0 + 32);
    short8 qf10 = *(const short8*)qp1,        qf11 = *(const short8*)(qp1 + 32);

    const int ia = i0 + r15, ib = ia + 16;       // this lane's two q-rows
    const float* rra = rdot + (size_t)(b * 1024 + ia) * NP + 128;
    const float* rrb = rra + 16 * NP;
    const float rvloA = rra[-128], rvhiA = rra[128];
    const float rvloB = rrb[-128], rvhiB = rrb[128];

    const int n0w = w * 256;
    // hoisted mask words: 4 u64 per row group cover this wave's 256 j
    unsigned long long mA[4], mB[4];
    {
        const size_t mbase = ((size_t)b << 14) + (((size_t)(n0w >> 6)) << 10);
        #pragma unroll
        for (int t = 0; t < 4; ++t) {
            mA[t] = mb[mbase + ((size_t)t << 10) + ia];
            mB[t] = mb[mbase + ((size_t)t << 10) + ib];
        }
    }

    float psA = 0.f, psB = 0.f;

    #pragma unroll 4
    for (int jt = 0; jt < 16; ++jt) {
        const int j0 = n0w + jt * 16;
        const unsigned short* kp = kb + qkbase + (size_t)(j0 + r15) * 1024 + 8 * g;
        short8 kf0 = *(const short8*)kp;
        short8 kf1 = *(const short8*)(kp + 32);
        f32x4 accA = (f32x4){0.f, 0.f, 0.f, 0.f};
        f32x4 accB = (f32x4){0.f, 0.f, 0.f, 0.f};
        accA = __builtin_amdgcn_mfma_f32_16x16x32_bf16(kf0, qf00, accA, 0, 0, 0);
        accB = __builtin_amdgcn_mfma_f32_16x16x32_bf16(kf0, qf10, accB, 0, 0, 0);
        accA = __builtin_amdgcn_mfma_f32_16x16x32_bf16(kf1, qf01, accA, 0, 0, 0);
        accB = __builtin_amdgcn_mfma_f32_16x16x32_bf16(kf1, qf11, accB, 0, 0, 0);

        const int jc = j0 + (g << 2);
        const int sh = (jt & 3) * 16 + (g << 2);
        const unsigned int nibA = (unsigned int)(mA[jt >> 2] >> sh) & 0xFu;
        const unsigned int nibB = (unsigned int)(mB[jt >> 2] >> sh) & 0xFu;

        // rel bias, row group A (rows i0..i0+15): uniform classification
        float ra0, ra1, ra2, ra3;
        if (j0 + 15 - i0 <= -129) {
            ra0 = ra1 = ra2 = ra3 = rvloA;
        } else if (j0 - (i0 + 15) >= 129) {
            ra0 = ra1 = ra2 = ra3 = rvhiA;
        } else {
            const int d0 = jc - ia;
            int dd;
            dd = min(max(d0 + 0, -128), 128); ra0 = rra[dd];
            dd = min(max(d0 + 1, -128), 128); ra1 = rra[dd];
            dd = min(max(d0 + 2, -128), 128); ra2 = rra[dd];
            dd = min(max(d0 + 3, -128), 128); ra3 = rra[dd];
        }
        // row group B (rows i0+16..i0+31)
        float rb0, rb1, rb2, rb3;
        if (j0 + 15 - (i0 + 16) <= -129) {
            rb0 = rb1 = rb2 = rb3 = rvloB;
        } else if (j0 - (i0 + 31) >= 129) {
            rb0 = rb1 = rb2 = rb3 = rvhiB;
        } else {
            const int d0 = jc - ib;
            int dd;
            dd = min(max(d0 + 0, -128), 128); rb0 = rrb[dd];
            dd = min(max(d0 + 1, -128), 128); rb1 = rrb[dd];
            dd = min(max(d0 + 2, -128), 128); rb2 = rrb[dd];
            dd = min(max(d0 + 3, -128), 128); rb3 = rrb[dd];
        }

        const float eA0 = (nibA & 1u) ? __expf(fmaf(accA[0], 0.125f, ra0)) : 0.f;
        const float eA1 = (nibA & 2u) ? __expf(fmaf(accA[1], 0.125f, ra1)) : 0.f;
        const float eA2 = (nibA & 4u) ? __expf(fmaf(accA[2], 0.125f, ra2)) : 0.f;
        const float eA3 = (nibA & 8u) ? __expf(fmaf(accA[3], 0.125f, ra3)) : 0.f;
        const float eB0 = (nibB & 1u) ? __expf(fmaf(accB[0], 0.125f, rb0)) : 0.f;
        const float eB1 = (nibB & 2u) ? __expf(fmaf(accB[1], 0.125f, rb1)) : 0.f;
        const float eB2 = (nibB & 4u) ? __expf(fmaf(accB[2], 0.125f, rb2)) : 0.f;
        const float eB3 = (nibB & 8u) ? __expf(fmaf(accB[3], 0.125f, rb3)) : 0.f;

        psA += (eA0 + eA1) + (eA2 + eA3);
        psB += (eB0 + eB1) + (eB2 + eB3);

        const unsigned int a0 = f32_to_bf16(eA0) | ((unsigned int)f32_to_bf16(eA1) << 16);
        const unsigned int a1 = f32_to_bf16(eA2) | ((unsigned int)f32_to_bf16(eA3) << 16);
        const unsigned int b0 = f32_to_bf16(eB0) | ((unsigned int)f32_to_bf16(eB1) << 16);
        const unsigned int b1 = f32_to_bf16(eB2) | ((unsigned int)f32_to_bf16(eB3) << 16);
        // add-rotate swizzle: col' = (col + row*4) & 1023
        const int usA = r15 * 1024 + ((jc + r15 * 4) & 1023);
        const int usB = (16 + r15) * 1024 + ((jc + (16 + r15) * 4) & 1023);
        *reinterpret_cast<uint2*>(&e_lds[usA]) = make_uint2(a0, a1);
        *reinterpret_cast<uint2*>(&e_lds[usB]) = make_uint2(b0, b1);
    }

    // row sums: combine the 4 g-groups (lanes with same r15)
    psA += __shfl_xor(psA, 16, 64);
    psA += __shfl_xor(psA, 32, 64);
    psB += __shfl_xor(psB, 16, 64);
    psB += __shfl_xor(psB, 32, 64);
    if (lane < 16) {
        redsum[w][r15] = psA;
        redsum[w][16 + r15] = psB;
    }
    __syncthreads();

    // normalize + store: wave w -> rows 8w..8w+7, coalesced float4 stores
    #pragma unroll
    for (int rr8 = 0; rr8 < 8; ++rr8) {
        const int rl = w * 8 + rr8;
        const float inv = 1.0f / (redsum[0][rl] + redsum[1][rl] + redsum[2][rl] + redsum[3][rl]);
        float* op = out + (((size_t)((b * 16 + h) * 1024 + i0 + rl)) << 10);
        #pragma unroll
        for (int n = 0; n < 4; ++n) {
            const int c = n * 256 + lane * 4;
            const int us = rl * 1024 + ((c + rl * 4) & 1023);
            uint2 u = *reinterpret_cast<const uint2*>(&e_lds[us]);
            float4 v;
            v.x = bf16_to_f32((unsigned short)(u.x & 0xFFFFu)) * inv;
            v.y = bf16_to_f32((unsigned short)(u.x >> 16)) * inv;
            v.z = bf16_to_f32((unsigned short)(u.y & 0xFFFFu)) * inv;
            v.w = bf16_to_f32((unsigned short)(u.y >> 16)) * inv;
            *reinterpret_cast<float4*>(op + c) = v;
        }
    }
}

extern "C" void kernel_launch(void* const* d_in, const int* in_sizes, int n_in,
                              void* d_out, int out_size, void* d_ws, size_t ws_size,
                              hipStream_t stream) {
    const float* query = (const float*)d_in[0];
    const float* key   = (const float*)d_in[1];
    const int*   mask  = (const int*)d_in[2];
    const float* Wq    = (const float*)d_in[3];
    const float* bq    = (const float*)d_in[4];
    const float* Wk    = (const float*)d_in[5];
    const float* bk    = (const float*)d_in[6];
    const float* relk  = (const float*)d_in[7];

    char* ws = (char*)d_ws;
    unsigned short* qB     = (unsigned short*)(ws);                  // 8 MB  q bf16
    unsigned short* kB     = (unsigned short*)(ws + (8u  << 20));    // 8 MB  k bf16
    unsigned short* queryb = (unsigned short*)(ws + (16u << 20));    // 8 MB (dead after proj)
    unsigned short* keyb   = (unsigned short*)(ws + (24u << 20));    // 8 MB (dead after proj)
    unsigned short* Wqb    = (unsigned short*)(ws + (32u << 20));    // 2 MB
    unsigned short* Wkb    = (unsigned short*)(ws + (34u << 20));    // 2 MB
    float*          rdot   = (float*)(ws + (37u << 20));             // 4.21 MB
    unsigned long long* mbB = (unsigned long long*)(ws + (16u << 20)); // 512 KB, after proj
    float*          out    = (float*)d_out;

    cvt_bf16_2<<<dim3(2048, 2), 256, 0, stream>>>(query, queryb, key, keyb, 524288);
    cvt_bf16_2<<<dim3(512, 2),  256, 0, stream>>>(Wq, Wqb, Wk, Wkb, 131072);

    proj_mfma<<<dim3(32, 8, 2), 256, 0, stream>>>(queryb, Wqb, bq, qB,
                                                  keyb,   Wkb, bk, kB);

    relrow<<<4096, 256, 0, stream>>>(qB, relk, rdot);
    maskbits<<<4096, 1024, 0, stream>>>(mask, mbB);

    attn4<<<dim3(32, 16, 4), 256, 0, stream>>>(qB, kB, mbB, rdot, out);
}

// Round 8
// 166.186 us; speedup vs baseline: 1.8224x; 1.1083x over previous
//
#include <hip/hip_runtime.h>
#include <hip/hip_bf16.h>

// B=4, S=1024, D=1024, H=16, d_k=64, MAX_REL=128 (NP=257)
#define NP 257

typedef __attribute__((ext_vector_type(8))) short short8;
typedef __attribute__((ext_vector_type(4))) float f32x4;

__device__ __forceinline__ unsigned short f32_to_bf16(float f) {
    unsigned int u = __float_as_uint(f);
    unsigned int r = (u + 0x7FFFu + ((u >> 16) & 1u)) >> 16;
    return (unsigned short)r;
}
__device__ __forceinline__ float bf16_to_f32(unsigned short u) {
    return __uint_as_float(((unsigned int)u) << 16);
}
__device__ __forceinline__ float bf16_lo(unsigned int u) {
    return __uint_as_float(u << 16);
}
__device__ __forceinline__ float bf16_hi(unsigned int u) {
    return __uint_as_float(u & 0xFFFF0000u);
}

// ---------------- fp32 -> bf16 pack, 8 elems/thread; grid.y selects buffer pair
__global__ __launch_bounds__(256) void cvt_bf16_2(const float* __restrict__ s0,
                                                  unsigned short* __restrict__ d0,
                                                  const float* __restrict__ s1,
                                                  unsigned short* __restrict__ d1,
                                                  int n8)
{
    int i = blockIdx.x * 256 + threadIdx.x;
    if (i >= n8) return;
    const float* src = blockIdx.y ? s1 : s0;
    unsigned short* dst = blockIdx.y ? d1 : d0;
    const float4* s = reinterpret_cast<const float4*>(src) + (size_t)i * 2;
    float4 a = s[0], b = s[1];
    union { unsigned short u[8]; uint4 v; } p;
    p.u[0] = f32_to_bf16(a.x); p.u[1] = f32_to_bf16(a.y);
    p.u[2] = f32_to_bf16(a.z); p.u[3] = f32_to_bf16(a.w);
    p.u[4] = f32_to_bf16(b.x); p.u[5] = f32_to_bf16(b.y);
    p.u[6] = f32_to_bf16(b.z); p.u[7] = f32_to_bf16(b.w);
    reinterpret_cast<uint4*>(dst)[i] = p.v;
}

// ---------------- MFMA projection, both GEMMs in one dispatch (blockIdx.z).
// Tile 128x128x64, 256 thr = 4 waves (2x2), wave tile 64x64 (4x4 frags).
__global__ __launch_bounds__(256) void proj_mfma(const unsigned short* __restrict__ Xq,
                                                 const unsigned short* __restrict__ Wqb,
                                                 const float* __restrict__ bq,
                                                 unsigned short* __restrict__ outq,
                                                 const unsigned short* __restrict__ Xk,
                                                 const unsigned short* __restrict__ Wkb,
                                                 const float* __restrict__ bk,
                                                 unsigned short* __restrict__ outk)
{
    __shared__ unsigned short As[8192];
    __shared__ unsigned short Bs[8192];
    const unsigned short* Xb = blockIdx.z ? Xk : Xq;
    const unsigned short* Wb = blockIdx.z ? Wkb : Wqb;
    const float* bias        = blockIdx.z ? bk : bq;
    unsigned short* outb     = blockIdx.z ? outk : outq;

    const int tid = threadIdx.x;
    const int lane = tid & 63;
    const int w = tid >> 6;
    const int wi = w >> 1, wj = w & 1;
    const int bm = blockIdx.x * 128, bn = blockIdx.y * 128;
    const int r15 = lane & 15, g = lane >> 4;

    f32x4 acc[4][4];
    #pragma unroll
    for (int i = 0; i < 4; ++i)
        #pragma unroll
        for (int j = 0; j < 4; ++j) acc[i][j] = (f32x4){0.f, 0.f, 0.f, 0.f};

    size_t offA[4], offB[4];
    #pragma unroll
    for (int it = 0; it < 4; ++it) {
        int f = it * 256 + tid, row = f >> 3, cl = (f & 7) ^ (row & 7);
        offA[it] = (size_t)(bm + row) * 1024 + cl * 8;
        offB[it] = (size_t)(bn + row) * 1024 + cl * 8;
    }
    const int ldsbase = w * 512;

    for (int kt = 0; kt < 16; ++kt) {
        const int k0 = kt * 64;
        #pragma unroll
        for (int it = 0; it < 4; ++it)
            __builtin_amdgcn_global_load_lds(
                (const __attribute__((address_space(1))) void*)(Xb + offA[it] + k0),
                (__attribute__((address_space(3))) void*)(As + it * 2048 + ldsbase), 16, 0, 0);
        #pragma unroll
        for (int it = 0; it < 4; ++it)
            __builtin_amdgcn_global_load_lds(
                (const __attribute__((address_space(1))) void*)(Wb + offB[it] + k0),
                (__attribute__((address_space(3))) void*)(Bs + it * 2048 + ldsbase), 16, 0, 0);
        __syncthreads();

        #pragma unroll
        for (int kk = 0; kk < 2; ++kk) {
            const int c = kk * 4 + g;
            short8 a[4], bfr[4];
            #pragma unroll
            for (int ti = 0; ti < 4; ++ti) {
                const int ra = wi * 64 + ti * 16 + r15;
                a[ti] = *(const short8*)&As[(ra * 8 + (c ^ (ra & 7))) * 8];
            }
            #pragma unroll
            for (int tj = 0; tj < 4; ++tj) {
                const int rb = wj * 64 + tj * 16 + r15;
                bfr[tj] = *(const short8*)&Bs[(rb * 8 + (c ^ (rb & 7))) * 8];
            }
            #pragma unroll
            for (int ti = 0; ti < 4; ++ti)
                #pragma unroll
                for (int tj = 0; tj < 4; ++tj)
                    acc[ti][tj] = __builtin_amdgcn_mfma_f32_16x16x32_bf16(a[ti], bfr[tj], acc[ti][tj], 0, 0, 0);
        }
        __syncthreads();
    }

    #pragma unroll
    for (int tj = 0; tj < 4; ++tj) {
        const int n = bn + wj * 64 + tj * 16 + r15;
        const float bv = bias[n];
        #pragma unroll
        for (int ti = 0; ti < 4; ++ti) {
            const int orow = bm + wi * 64 + ti * 16 + (g << 2);
            #pragma unroll
            for (int r = 0; r < 4; ++r)
                outb[(size_t)(orow + r) * 1024 + n] = f32_to_bf16(acc[ti][tj][r] + bv);
        }
    }
}

// ---------------- biasrow: per (b,i) fused qmean + reldot + mask -> bf16 bias row
// bias_bf[b,i,j] = mask[b,i,j] ? scale*dot(qmean[b,i], relk[clip(j-i)+128]) : -1e9
__global__ __launch_bounds__(256) void biasrow(const unsigned short* __restrict__ qb,
                                               const float* __restrict__ relk,
                                               const int* __restrict__ mask,
                                               unsigned short* __restrict__ biasbf)
{
    __shared__ __align__(16) float qm[64];
    __shared__ float rd[NP];
    const int bi = blockIdx.x;                  // b*1024 + i, 4096 blocks
    const int i = bi & 1023;
    const int t = threadIdx.x;
    if (t < 64) {
        const unsigned short* qrow = qb + ((size_t)bi << 10);
        float s = 0.f;
        #pragma unroll
        for (int h2 = 0; h2 < 16; ++h2) s += bf16_to_f32(qrow[h2 * 64 + t]);
        qm[t] = s * 0.0625f;
    }
    __syncthreads();
    const float4* qm4 = reinterpret_cast<const float4*>(qm);
    for (int p = t; p < NP; p += 256) {
        const float4* rk4 = reinterpret_cast<const float4*>(relk + (size_t)p * 64);
        float s0 = 0.f, s1 = 0.f, s2 = 0.f, s3 = 0.f;
        #pragma unroll
        for (int d4 = 0; d4 < 16; ++d4) {
            float4 a = qm4[d4];
            float4 b = rk4[d4];
            s0 = fmaf(a.x, b.x, s0);
            s1 = fmaf(a.y, b.y, s1);
            s2 = fmaf(a.z, b.z, s2);
            s3 = fmaf(a.w, b.w, s3);
        }
        rd[p] = (s0 + s1 + s2 + s3) * 0.125f;
    }
    __syncthreads();

    // 1024 outputs, 4 per thread
    const int4 mk = reinterpret_cast<const int4*>(mask + ((size_t)bi << 10))[t];
    const int j0 = t * 4;
    int d;
    float v0, v1, v2, v3;
    d = min(max(j0 + 0 - i, -128), 128); v0 = mk.x ? rd[d + 128] : -1e9f;
    d = min(max(j0 + 1 - i, -128), 128); v1 = mk.y ? rd[d + 128] : -1e9f;
    d = min(max(j0 + 2 - i, -128), 128); v2 = mk.z ? rd[d + 128] : -1e9f;
    d = min(max(j0 + 3 - i, -128), 128); v3 = mk.w ? rd[d + 128] : -1e9f;
    uint2 pk;
    pk.x = f32_to_bf16(v0) | ((unsigned int)f32_to_bf16(v1) << 16);
    pk.y = f32_to_bf16(v2) | ((unsigned int)f32_to_bf16(v3) << 16);
    *reinterpret_cast<uint2*>(biasbf + ((size_t)bi << 10) + j0) = pk;
}

// ---------------- attn5: QBLK=32, one-pass fused exp, branch-free epilogue.
// Block 256 thr / 4 waves: rows i0..i0+31 (two 16-row groups), wave w owns
// j in [256w, 256w+256). Swapped mfma(K,Q): lane r15 = q-row within group,
// owns 4 consecutive j. Epilogue = load bf16 bias (mask folded in as -1e9),
// fmaf + exp, pack bf16 -> LDS; then row-sum + normalize + coalesced store.
__global__ __launch_bounds__(256) void attn5(const unsigned short* __restrict__ qb,
                                             const unsigned short* __restrict__ kb,
                                             const unsigned short* __restrict__ biasbf,
                                             float* __restrict__ out)
{
    __shared__ unsigned short e_lds[32 * 1024];   // 64 KB
    __shared__ float redsum[4][32];
    const int i0 = blockIdx.x * 32;
    const int h = blockIdx.y, b = blockIdx.z;
    const int tid = threadIdx.x, lane = tid & 63, w = tid >> 6;
    const int r15 = lane & 15, g = lane >> 4;
    const size_t qkbase = ((size_t)b << 20) + h * 64;

    const unsigned short* qp0 = qb + qkbase + (size_t)(i0 + r15) * 1024 + 8 * g;
    const unsigned short* qp1 = qp0 + (16 << 10);
    short8 qf00 = *(const short8*)qp0,        qf01 = *(const short8*)(qp0 + 32);
    short8 qf10 = *(const short8*)qp1,        qf11 = *(const short8*)(qp1 + 32);

    const int ia = i0 + r15, ib = ia + 16;
    const unsigned short* bba = biasbf + (((size_t)(b * 1024 + ia)) << 10);
    const unsigned short* bbb = bba + (16 << 10);

    const int n0w = w * 256;
    float psA = 0.f, psB = 0.f;

    #pragma unroll 4
    for (int jt = 0; jt < 16; ++jt) {
        const int j0 = n0w + jt * 16;
        const unsigned short* kp = kb + qkbase + (size_t)(j0 + r15) * 1024 + 8 * g;
        short8 kf0 = *(const short8*)kp;
        short8 kf1 = *(const short8*)(kp + 32);
        f32x4 accA = (f32x4){0.f, 0.f, 0.f, 0.f};
        f32x4 accB = (f32x4){0.f, 0.f, 0.f, 0.f};
        accA = __builtin_amdgcn_mfma_f32_16x16x32_bf16(kf0, qf00, accA, 0, 0, 0);
        accB = __builtin_amdgcn_mfma_f32_16x16x32_bf16(kf0, qf10, accB, 0, 0, 0);
        accA = __builtin_amdgcn_mfma_f32_16x16x32_bf16(kf1, qf01, accA, 0, 0, 0);
        accB = __builtin_amdgcn_mfma_f32_16x16x32_bf16(kf1, qf11, accB, 0, 0, 0);

        const int jc = j0 + (g << 2);
        const uint2 bva = *reinterpret_cast<const uint2*>(bba + jc);
        const uint2 bvb = *reinterpret_cast<const uint2*>(bbb + jc);

        const float eA0 = __expf(fmaf(accA[0], 0.125f, bf16_lo(bva.x)));
        const float eA1 = __expf(fmaf(accA[1], 0.125f, bf16_hi(bva.x)));
        const float eA2 = __expf(fmaf(accA[2], 0.125f, bf16_lo(bva.y)));
        const float eA3 = __expf(fmaf(accA[3], 0.125f, bf16_hi(bva.y)));
        const float eB0 = __expf(fmaf(accB[0], 0.125f, bf16_lo(bvb.x)));
        const float eB1 = __expf(fmaf(accB[1], 0.125f, bf16_hi(bvb.x)));
        const float eB2 = __expf(fmaf(accB[2], 0.125f, bf16_lo(bvb.y)));
        const float eB3 = __expf(fmaf(accB[3], 0.125f, bf16_hi(bvb.y)));

        psA += (eA0 + eA1) + (eA2 + eA3);
        psB += (eB0 + eB1) + (eB2 + eB3);

        const unsigned int a0 = f32_to_bf16(eA0) | ((unsigned int)f32_to_bf16(eA1) << 16);
        const unsigned int a1 = f32_to_bf16(eA2) | ((unsigned int)f32_to_bf16(eA3) << 16);
        const unsigned int b0 = f32_to_bf16(eB0) | ((unsigned int)f32_to_bf16(eB1) << 16);
        const unsigned int b1 = f32_to_bf16(eB2) | ((unsigned int)f32_to_bf16(eB3) << 16);
        // add-rotate swizzle: col' = (col + row*4) & 1023
        const int usA = r15 * 1024 + ((jc + r15 * 4) & 1023);
        const int usB = (16 + r15) * 1024 + ((jc + (16 + r15) * 4) & 1023);
        *reinterpret_cast<uint2*>(&e_lds[usA]) = make_uint2(a0, a1);
        *reinterpret_cast<uint2*>(&e_lds[usB]) = make_uint2(b0, b1);
    }

    psA += __shfl_xor(psA, 16, 64);
    psA += __shfl_xor(psA, 32, 64);
    psB += __shfl_xor(psB, 16, 64);
    psB += __shfl_xor(psB, 32, 64);
    if (lane < 16) {
        redsum[w][r15] = psA;
        redsum[w][16 + r15] = psB;
    }
    __syncthreads();

    #pragma unroll
    for (int rr8 = 0; rr8 < 8; ++rr8) {
        const int rl = w * 8 + rr8;
        const float inv = 1.0f / (redsum[0][rl] + redsum[1][rl] + redsum[2][rl] + redsum[3][rl]);
        float* op = out + (((size_t)((b * 16 + h) * 1024 + i0 + rl)) << 10);
        #pragma unroll
        for (int n = 0; n < 4; ++n) {
            const int c = n * 256 + lane * 4;
            const int us = rl * 1024 + ((c + rl * 4) & 1023);
            uint2 u = *reinterpret_cast<const uint2*>(&e_lds[us]);
            float4 v;
            v.x = bf16_to_f32((unsigned short)(u.x & 0xFFFFu)) * inv;
            v.y = bf16_to_f32((unsigned short)(u.x >> 16)) * inv;
            v.z = bf16_to_f32((unsigned short)(u.y & 0xFFFFu)) * inv;
            v.w = bf16_to_f32((unsigned short)(u.y >> 16)) * inv;
            *reinterpret_cast<float4*>(op + c) = v;
        }
    }
}

extern "C" void kernel_launch(void* const* d_in, const int* in_sizes, int n_in,
                              void* d_out, int out_size, void* d_ws, size_t ws_size,
                              hipStream_t stream) {
    const float* query = (const float*)d_in[0];
    const float* key   = (const float*)d_in[1];
    const int*   mask  = (const int*)d_in[2];
    const float* Wq    = (const float*)d_in[3];
    const float* bq    = (const float*)d_in[4];
    const float* Wk    = (const float*)d_in[5];
    const float* bk    = (const float*)d_in[6];
    const float* relk  = (const float*)d_in[7];

    char* ws = (char*)d_ws;
    unsigned short* qB     = (unsigned short*)(ws);                  // 8 MB  q bf16
    unsigned short* kB     = (unsigned short*)(ws + (8u  << 20));    // 8 MB  k bf16
    unsigned short* queryb = (unsigned short*)(ws + (16u << 20));    // 8 MB (dead after proj)
    unsigned short* keyb   = (unsigned short*)(ws + (24u << 20));    // 8 MB (dead after proj)
    unsigned short* Wqb    = (unsigned short*)(ws + (32u << 20));    // 2 MB
    unsigned short* Wkb    = (unsigned short*)(ws + (34u << 20));    // 2 MB
    unsigned short* biasbf = (unsigned short*)(ws + (36u << 20));    // 8 MB bf16 bias
    float*          out    = (float*)d_out;

    cvt_bf16_2<<<dim3(2048, 2), 256, 0, stream>>>(query, queryb, key, keyb, 524288);
    cvt_bf16_2<<<dim3(512, 2),  256, 0, stream>>>(Wq, Wqb, Wk, Wkb, 131072);

    proj_mfma<<<dim3(32, 8, 2), 256, 0, stream>>>(queryb, Wqb, bq, qB,
                                                  keyb,   Wkb, bk, kB);

    biasrow<<<4096, 256, 0, stream>>>(qB, relk, mask, biasbf);

    attn5<<<dim3(32, 16, 4), 256, 0, stream>>>(qB, kB, biasbf, out);
}